// Round 10
// baseline (187.666 us; speedup 1.0000x reference)
//
#include <hip/hip_runtime.h>

// LRN_19705309954750 — cross-channel banded LRN on [B=64, C=128, H=56, W=56] fp32.
// y[c] = sum_{d=-8..8} x[(c+d)%128]^2 ; out = x * (y*ALPHA/17 + 1)^(-0.75)
//
// R14 post-mortem: absmax 7.95 — root cause: producer's global_load_lds source
// pointer was WAVE-UNIFORM. gll semantics: LDS dest = uniform + lane*16, but
// the GLOBAL source is PER-LANE. All 64 lanes loaded the same 16 B and
// scattered it. Fix: src = pb + chp*HW4 + LANE (+ chunk offsets). Barrier
// matching (65=65), ring slack (chunk c written steps c-22..c-17, last read
// c-23), and vmcnt math (7 insts/chunk, vmcnt(35) = 5 chunks in flight,
// chunk 17+j guaranteed at barrier j) re-audited and unchanged.
// H3 (untested due to the bug): the 2.4-2.9 TB/s plateau across ALL prior
// structures is caused by 0.5-1 KB read granules at 12.5 KB stride;
// fillBuffer (sequential) hits 6.8 TB/s at 9% occupancy in the same traces.
// R15 streams 6272 B CONTIGUOUS chunks, pure-load vmcnt, never drains:
// 256 blocks (1/CU) x {wave0 producer, waves1-7 consumers}, 24-slot LDS ring.
// Amp 1.25 -> 229 MB cache-side -> 36 us floor. If still ~60 us: the strided
// pattern itself is the memory ceiling -> roofline.

#define HW4   784                // float4 per full plane (56*56/4)
#define HALF4 392                // float4 per half-plane chunk (6272 B)
#define RING  24                 // LDS ring slots (24 * 6272 B = 150528 B)
#define NSTEP 64                 // output channels per job
#define NCHNK 80                 // chunks streamed per job (64 + 16 halo)

typedef __attribute__((address_space(3))) unsigned int lds_u32;
typedef __attribute__((address_space(1))) const unsigned int glb_u32;

__device__ __forceinline__ float pow_m075(float t) {
    // t in [1, ~1.01]; HW log2 + exp2 (~1 ulp each) — far inside 0.108 absmax
    return __builtin_amdgcn_exp2f(-0.75f * __builtin_amdgcn_logf(t));
}

__global__ __launch_bounds__(512, 1) void lrn_kernel(const float4* __restrict__ x,
                                                     float4* __restrict__ out) {
    const float kAlphaOverR = 0.001f / 17.0f;

    __shared__ float4 ring[RING * HALF4];      // 150528 B

    const int tid  = threadIdx.x;
    const int wave = tid >> 6;

    const int blk  = blockIdx.x;               // 256 jobs, 1 per CU
    const int b    = blk >> 2;
    const int h    = (blk >> 1) & 1;           // hw-half
    const int band = (blk & 1) << 6;           // channel band: 0 or 64

    if (wave == 0) {
        // ---------------- producer (64 lanes, no stores ever) ----------------
        const int lane = tid & 63;
        const float4* pb = x + ((size_t)b * 128) * HW4 + h * HALF4 + lane; // PER-LANE
        int chp  = (band + 120) & 127;         // channel of next chunk (band-8)
        int slot = 0;                          // ring slot of next chunk

        // issue one 6272B chunk: 7 gll, f4 offsets 0..320,328; last overlaps.
        // lane l of inst at offset o loads f4 (o + l) of the chunk -> LDS
        // dest base + l*16 (linear ✓, matches per-lane source ✓).
        auto issue = [&]() {
            const float4* s = pb + (size_t)chp * HW4;
            float4* d = &ring[slot * HALF4];
            __builtin_amdgcn_global_load_lds((glb_u32*)(s +   0), (lds_u32*)(d +   0), 16, 0, 0);
            __builtin_amdgcn_global_load_lds((glb_u32*)(s +  64), (lds_u32*)(d +  64), 16, 0, 0);
            __builtin_amdgcn_global_load_lds((glb_u32*)(s + 128), (lds_u32*)(d + 128), 16, 0, 0);
            __builtin_amdgcn_global_load_lds((glb_u32*)(s + 192), (lds_u32*)(d + 192), 16, 0, 0);
            __builtin_amdgcn_global_load_lds((glb_u32*)(s + 256), (lds_u32*)(d + 256), 16, 0, 0);
            __builtin_amdgcn_global_load_lds((glb_u32*)(s + 320), (lds_u32*)(d + 320), 16, 0, 0);
            __builtin_amdgcn_global_load_lds((glb_u32*)(s + 328), (lds_u32*)(d + 328), 16, 0, 0);
            chp = (chp + 1) & 127;
            slot = (slot + 1 == RING) ? 0 : slot + 1;
        };

        // prologue: chunks 0..21 (planes band-8 .. band+13)
        for (int p = 0; p < 22; ++p) issue();
        // chunks 0..16 resident (5 newest chunks = 35 insts may stay in flight)
        asm volatile("s_waitcnt vmcnt(35)" ::: "memory");
        __builtin_amdgcn_s_barrier();          // pre-barrier: release step 0

        // steady state: step j issues chunk 22+j, guarantees chunk 17+j
        for (int j = 0; j < 58; ++j) {
            issue();
            asm volatile("s_waitcnt vmcnt(35)" ::: "memory");
            __builtin_amdgcn_s_barrier();      // barrier_j
        }
        // tail: no more issues; progressively guarantee chunks 75..79
        asm volatile("s_waitcnt vmcnt(28)" ::: "memory"); __builtin_amdgcn_s_barrier(); // j=58
        asm volatile("s_waitcnt vmcnt(21)" ::: "memory"); __builtin_amdgcn_s_barrier(); // j=59
        asm volatile("s_waitcnt vmcnt(14)" ::: "memory"); __builtin_amdgcn_s_barrier(); // j=60
        asm volatile("s_waitcnt vmcnt(7)"  ::: "memory"); __builtin_amdgcn_s_barrier(); // j=61
        asm volatile("s_waitcnt vmcnt(0)"  ::: "memory"); __builtin_amdgcn_s_barrier(); // j=62
        __builtin_amdgcn_s_barrier();                                                   // j=63
    } else {
        // ---------------- consumers (waves 1..7: 448 threads, 392 active) ----
        const int  ctid = tid - 64;
        const bool act  = ctid < HALF4;
        float4* op = out + ((size_t)(b * 128 + band)) * HW4 + h * HALF4 + ctid;

        __builtin_amdgcn_s_barrier();          // pre-barrier: chunks 0..16 ready

        // initial window: buffer chunks 0..16 (= channels band-8 .. band+8)
        float sx = 0.f, sy = 0.f, sz = 0.f, sw = 0.f;
        if (act) {
            for (int p = 0; p < 17; ++p) {
                const float4 v = ring[p * HALF4 + ctid];
                sx = fmaf(v.x, v.x, sx);
                sy = fmaf(v.y, v.y, sy);
                sz = fmaf(v.z, v.z, sz);
                sw = fmaf(v.w, v.w, sw);
            }
        }

        int ia = 16, id = 23, ix = 8;          // rolling ring slots: j+16, j-1, j+8
        for (int j = 0; j < NSTEP; ++j) {
            if (act) {
                if (j > 0) {                   // slide window j-1 -> j
                    const float4 a = ring[ia * HALF4 + ctid];   // chunk j+16 (fresh)
                    const float4 d = ring[id * HALF4 + ctid];   // chunk j-1  (old)
                    sx += a.x * a.x - d.x * d.x;
                    sy += a.y * a.y - d.y * d.y;
                    sz += a.z * a.z - d.z * d.z;
                    sw += a.w * a.w - d.w * d.w;
                }
                const float4 xc = ring[ix * HALF4 + ctid];      // chunk j+8 = ch band+j
                float4 o;
                o.x = xc.x * pow_m075(fmaf(sx, kAlphaOverR, 1.0f));
                o.y = xc.y * pow_m075(fmaf(sy, kAlphaOverR, 1.0f));
                o.z = xc.z * pow_m075(fmaf(sz, kAlphaOverR, 1.0f));
                o.w = xc.w * pow_m075(fmaf(sw, kAlphaOverR, 1.0f));
                *op = o;
                op += HW4;                     // next output channel plane
            }
            ia = (ia + 1 == RING) ? 0 : ia + 1;
            id = (id + 1 == RING) ? 0 : id + 1;
            ix = (ix + 1 == RING) ? 0 : ix + 1;
            __builtin_amdgcn_s_barrier();      // barrier_j: next chunk guaranteed
        }
    }
}

extern "C" void kernel_launch(void* const* d_in, const int* in_sizes, int n_in,
                              void* d_out, int out_size, void* d_ws, size_t ws_size,
                              hipStream_t stream) {
    const float4* x = (const float4*)d_in[0];   // [64,128,56,56] fp32
    // d_in[1] (inhiMat) is a constant circulant band — computed analytically, unused.
    float4* out = (float4*)d_out;

    // 256 blocks (1 per CU) x 512 threads. Wave 0 streams 80 contiguous-6KB
    // chunks through a 24-slot LDS ring with 5 chunks always in flight;
    // waves 1-7 consume via per-step raw barriers. No drain in steady state.
    dim3 grid(64 * 2 * 2);
    lrn_kernel<<<grid, 512, 0, stream>>>(x, out);
}

// Round 11
// 180.235 us; speedup vs baseline: 1.0412x; 1.0412x over previous
//
#include <hip/hip_runtime.h>

// LRN_19705309954750 — cross-channel banded LRN on [B=64, C=128, H=56, W=56] fp32.
// y[c] = sum_{d=-8..8} x[(c+d)%128]^2 ; out = x * (y*ALPHA/17 + 1)^(-0.75)
//
// R15 post-mortem: 6 KB contiguous chunks, 35 KB/CU permanently in flight,
// pure-load vmcnt, zero drains -> STILL 65.7us / 2.5 TB/s. H3 (granularity)
// falsified. Also write-granule falsified (R15's 6 KB contiguous writes are
// slower than R11's 256 B). Matrix now: MLP, occupancy, phases, sync, read
// granule, write granule, store-vmcnt pollution ALL exonerated. In-flight
// bytes (9 MB chip-wide = 4x latency-BW product) are not the constraint.
// R16: the one untested mechanism — the 98 MB output stream write-allocates
// through L2/L3 and evicts the input's cache residency mid-kernel (reads are
// ~50% L3-served: FETCH 50-63 MB vs 103 MB input). Output has ZERO reuse ->
// nontemporal stores (global_store_dwordx4 nt) keep the write stream out of
// the caches. Base = R11 verbatim (best: 60.0us, canonical staging, proven
// correct); single-change A/B. If dur stays 60±3us -> pattern ceiling ->
// declare roofline.

#define HW4 784                  // float4 columns per plane (56*56/4)
#define CSTR HW4                 // float4 stride: channel plane
#define BSTR4 (128 * HW4)        // float4 stride: batch image
#define NCOL4 (64 * HW4)         // 50176 float4 columns total
#define TILE 16                  // float4 columns staged per block
#define NBLK (NCOL4 / TILE)      // 3136 blocks

typedef __attribute__((address_space(3))) unsigned int lds_u32;
typedef __attribute__((address_space(1))) const unsigned int glb_u32;
typedef float f32x4 __attribute__((ext_vector_type(4)));

__device__ __forceinline__ float pow_m075(float t) {
    // t in [1, ~1.01]; HW log2 + exp2 (~1 ulp each) — far inside 0.108 absmax
    return __builtin_amdgcn_exp2f(-0.75f * __builtin_amdgcn_logf(t));
}

__global__ __launch_bounds__(256, 5) void lrn_kernel(const float4* __restrict__ x,
                                                     float4* __restrict__ out) {
    const float kAlphaOverR = 0.001f / 17.0f;

    __shared__ float4 lds[128 * TILE];     // 32 KB: lds[p*TILE + c] = plane p, col c

    const int tid  = threadIdx.x;
    const int lane = tid & 63;
    const int wave = tid >> 6;             // 0..3

    // ---- stage all 128 planes: 32 insts total, 8 per wave.
    //      inst q writes lds bytes [q*1024, q*1024+1024) = planes 4q..4q+3,
    //      lane l -> plane 4q + (l>>4), col l&15 (dest = uniform + lane*16 ✓,
    //      global src per-lane ✓)
    {
        const int cl    = lane & 15;                   // col within tile
        const int pp    = lane >> 4;                   // plane sub-index 0..3
        const int col4g = blockIdx.x * TILE + cl;      // global float4 column
        const int b     = col4g / HW4;
        const int hw4   = col4g - b * HW4;
        const float4* src0 = x + (size_t)b * BSTR4 + hw4 + (size_t)pp * CSTR;
#pragma unroll
        for (int j = 0; j < 8; ++j) {
            const int q = wave * 8 + j;                // plane-quad index 0..31
            __builtin_amdgcn_global_load_lds((glb_u32*)(src0 + (size_t)q * (4 * CSTR)),
                                             (lds_u32*)&lds[q * 64], 16, 0, 0);
        }
    }
    asm volatile("s_waitcnt vmcnt(0)" ::: "memory");   // drain ONCE per block
    __syncthreads();

    // ---- compute: thread -> (col = tid&15, 8 channels from ch0)
    const int c   = tid & 15;
    const int ch0 = (tid >> 4) * 8;                    // 0,8,...,120

    const int col4g = blockIdx.x * TILE + c;
    const int b     = col4g / HW4;
    const int hw4   = col4g - b * HW4;
    float4* obase   = out + (size_t)b * BSTR4 + hw4;

    // initial window sum: planes ch0-8 .. ch0+8 (mod 128)
    float sx = 0.f, sy = 0.f, sz = 0.f, sw = 0.f;
#pragma unroll
    for (int j = -8; j <= 8; ++j) {
        const float4 v = lds[((ch0 + j) & 127) * TILE + c];
        sx = fmaf(v.x, v.x, sx);
        sy = fmaf(v.y, v.y, sy);
        sz = fmaf(v.z, v.z, sz);
        sw = fmaf(v.w, v.w, sw);
    }

#pragma unroll
    for (int i = 0; i < 8; ++i) {
        const int ch = ch0 + i;                        // <= 127, never wraps
        const float4 xc = lds[ch * TILE + c];          // numerator plane
        f32x4 o;
        o.x = xc.x * pow_m075(fmaf(sx, kAlphaOverR, 1.0f));
        o.y = xc.y * pow_m075(fmaf(sy, kAlphaOverR, 1.0f));
        o.z = xc.z * pow_m075(fmaf(sz, kAlphaOverR, 1.0f));
        o.w = xc.w * pow_m075(fmaf(sw, kAlphaOverR, 1.0f));
        // NONTEMPORAL: output has zero reuse — bypass L2/L3 allocation so the
        // write stream cannot evict the input's cache residency.
        __builtin_nontemporal_store(o, (f32x4*)&obase[(size_t)ch * CSTR]);

        if (i < 7) {                                   // slide window mod 128
            const float4 a = lds[((ch + 9) & 127) * TILE + c];
            const float4 d = lds[((ch - 8) & 127) * TILE + c];
            sx += a.x * a.x - d.x * d.x;
            sy += a.y * a.y - d.y * d.y;
            sz += a.z * a.z - d.z * d.z;
            sw += a.w * a.w - d.w * d.w;
        }
    }
}

extern "C" void kernel_launch(void* const* d_in, const int* in_sizes, int n_in,
                              void* d_out, int out_size, void* d_ws, size_t ws_size,
                              hipStream_t stream) {
    const float4* x = (const float4*)d_in[0];   // [64,128,56,56] fp32
    // d_in[1] (inhiMat) is a constant circulant band — computed analytically, unused.
    float4* out = (float4*)d_out;

    // 3136 blocks x 256 threads; 32 KB LDS -> 5 blocks/CU, 20 waves/CU.
    // Amp 1.0 both directions; single change vs R11: nt stores.
    dim3 grid(NBLK);
    lrn_kernel<<<grid, 256, 0, stream>>>(x, out);
}